// Round 2
// baseline (1474.637 us; speedup 1.0000x reference)
//
#include <hip/hip_runtime.h>
#include <hip/hip_bf16.h>

// Problem constants
#define NN    8192
#define FEAT  64
#define HIDD  128
#define EMBD  128

typedef __bf16 bf16x8 __attribute__((ext_vector_type(8)));
typedef float  f32x4  __attribute__((ext_vector_type(4)));

// ---------------------------------------------------------------------------
// proj_pack: V_r = X @ W_r^T, stored as bf16 in MFMA B-fragment layout:
//   Vp[r][kb][n][lane][j],  kb = k/32 (256), n = col/16 (8), lane 0..63, j 0..7
//   element (lane,j) of fragment (kb,n) = V_r[kb*32 + (lane>>4)*8 + j][n*16 + (lane&15)]
// ---------------------------------------------------------------------------
template<int KIN>
__global__ __launch_bounds__(256) void proj_pack(
    const float* __restrict__ X, const float* __restrict__ W0,
    const float* __restrict__ W1, const float* __restrict__ W2,
    __bf16* __restrict__ Vp)
{
    size_t e = (size_t)blockIdx.x * 256 + threadIdx.x;   // < 3 * 2^20
    int j  = (int)(e & 7);
    int l  = (int)((e >> 3) & 63);
    int n  = (int)((e >> 9) & 7);
    int kb = (int)((e >> 12) & 255);
    int r  = (int)(e >> 20);
    int krow = kb * 32 + (l >> 4) * 8 + j;
    int col  = n * 16 + (l & 15);
    const float* w = (r == 0 ? W0 : (r == 1 ? W1 : W2)) + (size_t)col * KIN;
    const float* x = X + (size_t)krow * KIN;
    float s = 0.f;
#pragma unroll
    for (int t = 0; t < KIN; t += 4) {
        f32x4 xv = *(const f32x4*)(x + t);
        f32x4 wv = *(const f32x4*)(w + t);
        s += xv[0]*wv[0] + xv[1]*wv[1] + xv[2]*wv[2] + xv[3]*wv[3];
    }
    Vp[e] = (__bf16)s;
}

// ---------------------------------------------------------------------------
// gemm_AV: P[ch] = sum_r A_r[64 rows, 1024 K-chunk] @ V_r[chunk, 128]
// block: 256 thr = 4 waves; wave = 16 rows x 128 cols (1 m-frag, 8 n-frags)
// grid: (128 Mtiles, 8 chunks) = 1024 blocks -> 4 blocks/CU, 16 waves/CU.
// r-loop folded inside, accumulating into one acc (8 slabs instead of 12/24).
// A loaded f32 -> cvt bf16 in regs; B from packed Vp (cache-resident). No LDS.
// ---------------------------------------------------------------------------
__global__ __launch_bounds__(256) void gemm_AV(
    const float* __restrict__ A0, const float* __restrict__ A1,
    const float* __restrict__ A2,
    const __bf16* __restrict__ Vp, float* __restrict__ P)
{
    const int mt = blockIdx.x;            // 0..127
    const int ch = blockIdx.y;            // 0..7
    const int tid = threadIdx.x;
    const int w = tid >> 6, l = tid & 63;
    const int l15 = l & 15, l4 = l >> 4;
    const int rowbase = mt * 64 + w * 16;
    const int k0 = ch * 1024;

    f32x4 acc[8];
#pragma unroll
    for (int n = 0; n < 8; n++) acc[n] = (f32x4){0.f, 0.f, 0.f, 0.f};

    for (int r = 0; r < 3; ++r) {
        const float* A = (r == 0) ? A0 : (r == 1) ? A1 : A2;
        const float* ap = A + (size_t)(rowbase + l15) * NN + k0 + l4 * 8;
        const __bf16* bp = Vp + ((size_t)r << 20) + (size_t)(k0 >> 5) * 4096 + l * 8;
#pragma unroll 4
        for (int s = 0; s < 32; ++s) {            // 32 K-steps of 32
            f32x4 lo = *(const f32x4*)(ap + s * 32);
            f32x4 hi = *(const f32x4*)(ap + s * 32 + 4);
            bf16x8 af;
            af[0] = (__bf16)lo[0]; af[1] = (__bf16)lo[1];
            af[2] = (__bf16)lo[2]; af[3] = (__bf16)lo[3];
            af[4] = (__bf16)hi[0]; af[5] = (__bf16)hi[1];
            af[6] = (__bf16)hi[2]; af[7] = (__bf16)hi[3];
            const __bf16* b = bp + (size_t)s * 4096;
#pragma unroll
            for (int n = 0; n < 8; ++n) {
                bf16x8 bfrag = *(const bf16x8*)(b + n * 512);
                acc[n] = __builtin_amdgcn_mfma_f32_16x16x32_bf16(af, bfrag, acc[n], 0, 0, 0);
            }
        }
    }

    // C/D layout: col = lane&15, row = (lane>>4)*4 + i
    float* Pp = P + (size_t)ch * NN * 128;
#pragma unroll
    for (int n = 0; n < 8; n++) {
        int col = n * 16 + l15;
#pragma unroll
        for (int i = 0; i < 4; i++) {
            int row = rowbase + l4 * 4 + i;
            Pp[(size_t)row * 128 + col] = acc[n][i];
        }
    }
}

// ---------------------------------------------------------------------------
// reduce kernels: sum 8 partial slabs + bias (+relu), f32x4 vectorized
// ---------------------------------------------------------------------------
__global__ __launch_bounds__(256) void reduce_relu(
    const float* __restrict__ P, const float* __restrict__ bias,
    float* __restrict__ Hout)
{
    size_t g = (size_t)blockIdx.x * 256 + threadIdx.x;   // < 2^18
    size_t idx4 = g * 4;
    f32x4 s = *(const f32x4*)(bias + (idx4 & 127));
#pragma unroll
    for (int p = 0; p < 8; p++) s += *(const f32x4*)(P + (size_t)p * (NN * 128) + idx4);
#pragma unroll
    for (int c = 0; c < 4; c++) s[c] = s[c] > 0.f ? s[c] : 0.f;
    *(f32x4*)(Hout + idx4) = s;
}

__global__ __launch_bounds__(256) void reduce_z(
    const float* __restrict__ P, const float* __restrict__ bias,
    float* __restrict__ Zout, __bf16* __restrict__ Zb)
{
    size_t g = (size_t)blockIdx.x * 256 + threadIdx.x;
    size_t idx4 = g * 4;
    f32x4 s = *(const f32x4*)(bias + (idx4 & 127));
#pragma unroll
    for (int p = 0; p < 8; p++) s += *(const f32x4*)(P + (size_t)p * (NN * 128) + idx4);
    *(f32x4*)(Zout + idx4) = s;
#pragma unroll
    for (int c = 0; c < 4; c++) Zb[idx4 + c] = (__bf16)s[c];
}

// ---------------------------------------------------------------------------
// zzt: A_hat = Z @ Z^T, K=128, from row-major bf16 Z (2 MB, cache-resident)
// block: 4 waves, 128x128 tile; grid 64x64. Write-bound (268 MB).
// ---------------------------------------------------------------------------
__global__ __launch_bounds__(256) void zzt(
    const __bf16* __restrict__ Zb, float* __restrict__ Out)
{
    const int bx = blockIdx.x;   // col tile
    const int by = blockIdx.y;   // row tile
    const int tid = threadIdx.x;
    const int w = tid >> 6, l = tid & 63;
    const int l15 = l & 15, l4 = l >> 4;
    const int rowbase = by * 128 + w * 32;
    const int colbase = bx * 128;

    f32x4 acc[2][8];
#pragma unroll
    for (int m = 0; m < 2; m++)
#pragma unroll
        for (int n = 0; n < 8; n++) acc[m][n] = (f32x4){0.f, 0.f, 0.f, 0.f};

#pragma unroll
    for (int ks = 0; ks < 128; ks += 32) {
        bf16x8 af[2];
#pragma unroll
        for (int m = 0; m < 2; m++)
            af[m] = *(const bf16x8*)(Zb + (size_t)(rowbase + m * 16 + l15) * 128 + ks + l4 * 8);
#pragma unroll
        for (int n = 0; n < 8; n++) {
            bf16x8 bfr = *(const bf16x8*)(Zb + (size_t)(colbase + n * 16 + l15) * 128 + ks + l4 * 8);
            acc[0][n] = __builtin_amdgcn_mfma_f32_16x16x32_bf16(af[0], bfr, acc[0][n], 0, 0, 0);
            acc[1][n] = __builtin_amdgcn_mfma_f32_16x16x32_bf16(af[1], bfr, acc[1][n], 0, 0, 0);
        }
    }

#pragma unroll
    for (int m = 0; m < 2; m++)
#pragma unroll
        for (int n = 0; n < 8; n++) {
            int col = colbase + n * 16 + l15;
#pragma unroll
            for (int i = 0; i < 4; i++) {
                int row = rowbase + m * 16 + l4 * 4 + i;
                Out[(size_t)row * NN + col] = acc[m][n][i];
            }
        }
}

// ---------------------------------------------------------------------------
extern "C" void kernel_launch(void* const* d_in, const int* in_sizes, int n_in,
                              void* d_out, int out_size, void* d_ws, size_t ws_size,
                              hipStream_t stream)
{
    // setup_inputs() insertion order: H, A_buys, A_views, A_rates,
    //   W1_0, W2_0, W1_1, W2_1, W1_2, W2_2, b1, b2   (W1/W2 interleaved!)
    const float* H    = (const float*)d_in[0];
    const float* A0   = (const float*)d_in[1];
    const float* A1   = (const float*)d_in[2];
    const float* A2   = (const float*)d_in[3];
    const float* W1_0 = (const float*)d_in[4];
    const float* W2_0 = (const float*)d_in[5];
    const float* W1_1 = (const float*)d_in[6];
    const float* W2_1 = (const float*)d_in[7];
    const float* W1_2 = (const float*)d_in[8];
    const float* W2_2 = (const float*)d_in[9];
    const float* b1   = (const float*)d_in[10];
    const float* b2   = (const float*)d_in[11];

    float* Zout = (float*)d_out;                     // [8192][128]
    float* Ahat = (float*)d_out + (size_t)NN * EMBD; // [8192][8192]

    char* ws = (char*)d_ws;
    __bf16* Vp = (__bf16*)ws;                        //  6 MB packed V (3 x 2MB)
    float*  P  = (float*)(ws + ((size_t)8  << 20));  // 32 MB partials (8 slabs)
    float*  H1 = (float*)(ws + ((size_t)40 << 20));  //  4 MB
    __bf16* Zb = (__bf16*)(ws + ((size_t)44 << 20)); //  2 MB

    // Layer 1
    proj_pack<FEAT><<<12288, 256, 0, stream>>>(H, W1_0, W1_1, W1_2, Vp);
    gemm_AV<<<dim3(128, 8), 256, 0, stream>>>(A0, A1, A2, Vp, P);
    reduce_relu<<<1024, 256, 0, stream>>>(P, b1, H1);

    // Layer 2
    proj_pack<HIDD><<<12288, 256, 0, stream>>>(H1, W2_0, W2_1, W2_2, Vp);
    gemm_AV<<<dim3(128, 8), 256, 0, stream>>>(A0, A1, A2, Vp, P);
    reduce_z<<<1024, 256, 0, stream>>>(P, b2, Zout, Zb);

    // Decoder
    zzt<<<dim3(64, 64), 256, 0, stream>>>(Zb, Ahat);
}

// Round 3
// 875.507 us; speedup vs baseline: 1.6843x; 1.6843x over previous
//
#include <hip/hip_runtime.h>
#include <hip/hip_bf16.h>

// Problem constants
#define NN    8192
#define FEAT  64
#define HIDD  128
#define EMBD  128

typedef __bf16 bf16x8 __attribute__((ext_vector_type(8)));
typedef float  f32x4  __attribute__((ext_vector_type(4)));

__device__ __forceinline__ void gload16(const void* g, void* l) {
    __builtin_amdgcn_global_load_lds(
        (const __attribute__((address_space(1))) void*)g,
        (__attribute__((address_space(3))) void*)l, 16, 0, 0);
}

// ---------------------------------------------------------------------------
// proj_pack: V_r = X @ W_r^T, stored as bf16 in MFMA B-fragment layout:
//   Vp[r][kb][n][lane][j]: element = V_r[kb*32 + (lane>>4)*8 + j][n*16 + (lane&15)]
// ---------------------------------------------------------------------------
template<int KIN>
__global__ __launch_bounds__(256) void proj_pack(
    const float* __restrict__ X, const float* __restrict__ W0,
    const float* __restrict__ W1, const float* __restrict__ W2,
    __bf16* __restrict__ Vp)
{
    size_t e = (size_t)blockIdx.x * 256 + threadIdx.x;   // < 3 * 2^20
    int j  = (int)(e & 7);
    int l  = (int)((e >> 3) & 63);
    int n  = (int)((e >> 9) & 7);
    int kb = (int)((e >> 12) & 255);
    int r  = (int)(e >> 20);
    int krow = kb * 32 + (l >> 4) * 8 + j;
    int col  = n * 16 + (l & 15);
    const float* w = (r == 0 ? W0 : (r == 1 ? W1 : W2)) + (size_t)col * KIN;
    const float* x = X + (size_t)krow * KIN;
    float s = 0.f;
#pragma unroll
    for (int t = 0; t < KIN; t += 4) {
        f32x4 xv = *(const f32x4*)(x + t);
        f32x4 wv = *(const f32x4*)(w + t);
        s += xv[0]*wv[0] + xv[1]*wv[1] + xv[2]*wv[2] + xv[3]*wv[3];
    }
    Vp[e] = (__bf16)s;
}

// ---------------------------------------------------------------------------
// gemm_AV v3: LDS-staged, async global_load_lds, triple-buffered.
// Block: 128 thr (2 waves); tile 128 rows x 128 cols; K-chunk 1024; r folded.
// Per K-step (BK=32): stage A (16KB f32, XOR-swizzled) + B (8KB packed bf16)
// via 12 async 1KB loads/wave, one __syncthreads per step, compute 32 MFMA/wave.
// Grid (64 mt, 8 ch) = 512 blocks; LDS 72KB -> 2 blocks/CU.
// ---------------------------------------------------------------------------
__global__ __launch_bounds__(128, 2) void gemm_AV(
    const float* __restrict__ A0, const float* __restrict__ A1,
    const float* __restrict__ A2,
    const __bf16* __restrict__ Vp, float* __restrict__ P)
{
    __shared__ float  sA[3][4096];   // [buf][128 rows x 32 k], 16B-block-swizzled
    __shared__ __bf16 sB[3][4096];   // [buf][8 frags x 512]

    const int mt = blockIdx.x;            // 0..63  (128-row tile)
    const int ch = blockIdx.y;            // 0..7   (1024-K chunk)
    const int tid = threadIdx.x;
    const int w = tid >> 6, l = tid & 63;
    const int l15 = l & 15, l4 = l >> 4;

    // staging lane constants: row-within-8-group and swizzled 16B block
    const int srow = l >> 3;              // 0..7
    const int sblk = (l & 7) ^ srow;      // inverse-swizzled source block

    f32x4 acc[4][8];
#pragma unroll
    for (int m = 0; m < 4; m++)
#pragma unroll
        for (int n = 0; n < 8; n++) acc[m][n] = (f32x4){0.f, 0.f, 0.f, 0.f};

    const int rowblk = mt * 128 + w * 64;     // this wave's 64 rows

    // ---- stage step t into buffer t%3 ----
    auto stage = [&](int t) {
        const int r  = t >> 5;                 // 0..2
        const float* Ar = (r == 0) ? A0 : (r == 1) ? A1 : A2;
        const int kglob = ch * 1024 + (t & 31) * 32;
        const int b = t % 3;
        // A: 8 insts/wave, each 8 rows x 128B (source 16B blocks permuted by XOR)
        const float* asrc = Ar + (size_t)(rowblk + srow) * NN + kglob + sblk * 4;
        float* adst = &sA[b][w * 64 * 32];
#pragma unroll
        for (int j = 0; j < 8; ++j)
            gload16(asrc + (size_t)j * 8 * NN, adst + j * 256);
        // B: 4 insts/wave, linear (Vp already fragment-packed)
        const __bf16* bsrc = Vp + ((size_t)r << 20) + (size_t)(kglob >> 5) * 4096
                             + w * 2048 + l * 8;
        __bf16* bdst = &sB[b][w * 2048];
#pragma unroll
        for (int q = 0; q < 4; ++q)
            gload16(bsrc + q * 512, bdst + q * 512);
    };

    stage(0);

    for (int t = 0; t < 96; ++t) {
        if (t < 95) stage(t + 1);
        __syncthreads();                       // drains vmcnt: stage(t) complete
        const int b = t % 3;
        bf16x8 bf[8];
#pragma unroll
        for (int n = 0; n < 8; ++n)
            bf[n] = *(const bf16x8*)&sB[b][n * 512 + l * 8];
#pragma unroll
        for (int m = 0; m < 4; ++m) {
            const int row = w * 64 + m * 16 + l15;
            const int blk0 = (l4 * 2) ^ (l15 & 7);
            f32x4 a0 = *(const f32x4*)&sA[b][row * 32 + blk0 * 4];
            f32x4 a1 = *(const f32x4*)&sA[b][row * 32 + (blk0 ^ 1) * 4];
            bf16x8 af;
            af[0] = (__bf16)a0[0]; af[1] = (__bf16)a0[1];
            af[2] = (__bf16)a0[2]; af[3] = (__bf16)a0[3];
            af[4] = (__bf16)a1[0]; af[5] = (__bf16)a1[1];
            af[6] = (__bf16)a1[2]; af[7] = (__bf16)a1[3];
#pragma unroll
            for (int n = 0; n < 8; ++n)
                acc[m][n] = __builtin_amdgcn_mfma_f32_16x16x32_bf16(af, bf[n], acc[m][n], 0, 0, 0);
        }
    }

    // C/D layout: col = lane&15, row = (lane>>4)*4 + i
    float* Pp = P + (size_t)ch * NN * 128;
#pragma unroll
    for (int m = 0; m < 4; m++)
#pragma unroll
        for (int n = 0; n < 8; n++) {
            int col = n * 16 + l15;
#pragma unroll
            for (int i = 0; i < 4; i++) {
                int row = mt * 128 + w * 64 + m * 16 + l4 * 4 + i;
                Pp[(size_t)row * 128 + col] = acc[m][n][i];
            }
        }
}

// ---------------------------------------------------------------------------
// reduce kernels: sum 8 partial slabs + bias (+relu), f32x4 vectorized
// ---------------------------------------------------------------------------
__global__ __launch_bounds__(256) void reduce_relu(
    const float* __restrict__ P, const float* __restrict__ bias,
    float* __restrict__ Hout)
{
    size_t g = (size_t)blockIdx.x * 256 + threadIdx.x;   // < 2^18
    size_t idx4 = g * 4;
    f32x4 s = *(const f32x4*)(bias + (idx4 & 127));
#pragma unroll
    for (int p = 0; p < 8; p++) s += *(const f32x4*)(P + (size_t)p * (NN * 128) + idx4);
#pragma unroll
    for (int c = 0; c < 4; c++) s[c] = s[c] > 0.f ? s[c] : 0.f;
    *(f32x4*)(Hout + idx4) = s;
}

__global__ __launch_bounds__(256) void reduce_z(
    const float* __restrict__ P, const float* __restrict__ bias,
    float* __restrict__ Zout, __bf16* __restrict__ Zb)
{
    size_t g = (size_t)blockIdx.x * 256 + threadIdx.x;
    size_t idx4 = g * 4;
    f32x4 s = *(const f32x4*)(bias + (idx4 & 127));
#pragma unroll
    for (int p = 0; p < 8; p++) s += *(const f32x4*)(P + (size_t)p * (NN * 128) + idx4);
    *(f32x4*)(Zout + idx4) = s;
#pragma unroll
    for (int c = 0; c < 4; c++) Zb[idx4 + c] = (__bf16)s[c];
}

// ---------------------------------------------------------------------------
// zzt: A_hat = Z @ Z^T, K=128, from row-major bf16 Z (2 MB, cache-resident)
// ---------------------------------------------------------------------------
__global__ __launch_bounds__(256) void zzt(
    const __bf16* __restrict__ Zb, float* __restrict__ Out)
{
    const int bx = blockIdx.x;   // col tile
    const int by = blockIdx.y;   // row tile
    const int tid = threadIdx.x;
    const int w = tid >> 6, l = tid & 63;
    const int l15 = l & 15, l4 = l >> 4;
    const int rowbase = by * 128 + w * 32;
    const int colbase = bx * 128;

    f32x4 acc[2][8];
#pragma unroll
    for (int m = 0; m < 2; m++)
#pragma unroll
        for (int n = 0; n < 8; n++) acc[m][n] = (f32x4){0.f, 0.f, 0.f, 0.f};

#pragma unroll
    for (int ks = 0; ks < 128; ks += 32) {
        bf16x8 af[2];
#pragma unroll
        for (int m = 0; m < 2; m++)
            af[m] = *(const bf16x8*)(Zb + (size_t)(rowbase + m * 16 + l15) * 128 + ks + l4 * 8);
#pragma unroll
        for (int n = 0; n < 8; n++) {
            bf16x8 bfr = *(const bf16x8*)(Zb + (size_t)(colbase + n * 16 + l15) * 128 + ks + l4 * 8);
            acc[0][n] = __builtin_amdgcn_mfma_f32_16x16x32_bf16(af[0], bfr, acc[0][n], 0, 0, 0);
            acc[1][n] = __builtin_amdgcn_mfma_f32_16x16x32_bf16(af[1], bfr, acc[1][n], 0, 0, 0);
        }
    }

#pragma unroll
    for (int m = 0; m < 2; m++)
#pragma unroll
        for (int n = 0; n < 8; n++) {
            int col = colbase + n * 16 + l15;
#pragma unroll
            for (int i = 0; i < 4; i++) {
                int row = rowbase + m * 16 + l4 * 4 + i;
                Out[(size_t)row * NN + col] = acc[m][n][i];
            }
        }
}

// ---------------------------------------------------------------------------
extern "C" void kernel_launch(void* const* d_in, const int* in_sizes, int n_in,
                              void* d_out, int out_size, void* d_ws, size_t ws_size,
                              hipStream_t stream)
{
    // setup_inputs() order: H, A_buys, A_views, A_rates,
    //   W1_0, W2_0, W1_1, W2_1, W1_2, W2_2, b1, b2
    const float* H    = (const float*)d_in[0];
    const float* A0   = (const float*)d_in[1];
    const float* A1   = (const float*)d_in[2];
    const float* A2   = (const float*)d_in[3];
    const float* W1_0 = (const float*)d_in[4];
    const float* W2_0 = (const float*)d_in[5];
    const float* W1_1 = (const float*)d_in[6];
    const float* W2_1 = (const float*)d_in[7];
    const float* W1_2 = (const float*)d_in[8];
    const float* W2_2 = (const float*)d_in[9];
    const float* b1   = (const float*)d_in[10];
    const float* b2   = (const float*)d_in[11];

    float* Zout = (float*)d_out;                     // [8192][128]
    float* Ahat = (float*)d_out + (size_t)NN * EMBD; // [8192][8192]

    char* ws = (char*)d_ws;
    __bf16* Vp = (__bf16*)ws;                        //  6 MB packed V (3 x 2MB)
    float*  P  = (float*)(ws + ((size_t)8  << 20));  // 32 MB partials (8 slabs)
    float*  H1 = (float*)(ws + ((size_t)40 << 20));  //  4 MB
    __bf16* Zb = (__bf16*)(ws + ((size_t)44 << 20)); //  2 MB

    // Layer 1
    proj_pack<FEAT><<<12288, 256, 0, stream>>>(H, W1_0, W1_1, W1_2, Vp);
    gemm_AV<<<dim3(64, 8), 128, 0, stream>>>(A0, A1, A2, Vp, P);
    reduce_relu<<<1024, 256, 0, stream>>>(P, b1, H1);

    // Layer 2
    proj_pack<HIDD><<<12288, 256, 0, stream>>>(H1, W2_0, W2_1, W2_2, Vp);
    gemm_AV<<<dim3(64, 8), 128, 0, stream>>>(A0, A1, A2, Vp, P);
    reduce_z<<<1024, 256, 0, stream>>>(P, b2, Zout, Zb);

    // Decoder
    zzt<<<dim3(64, 64), 256, 0, stream>>>(Zb, Ahat);
}